// Round 16
// baseline (101.654 us; speedup 1.0000x reference)
//
#include <hip/hip_runtime.h>
#include <hip/hip_bf16.h>
#include <math.h>

#define B_   32
#define J_   1182      // V*P = 6*197
#define D_   512
#define L_   77
#define C_   5
#define JC_  64        // j-chunk for ftf
#define NCH_ 19        // ceil(1182/64)
#define NPW_ 37        // pw chunks of 32 rows

__device__ __forceinline__ float dot4(float4 a, float4 b) {
    return a.x*b.x + a.y*b.y + a.z*b.z + a.w*b.w;
}

__device__ __forceinline__ float wave_sum(float v) {
#pragma unroll
    for (int off = 32; off > 0; off >>= 1) v += __shfl_xor(v, off, 64);
    return v;
}

__device__ __forceinline__ float wave_max(float v) {
#pragma unroll
    for (int off = 32; off > 0; off >>= 1) v = fmaxf(v, __shfl_xor(v, off, 64));
    return v;
}

// K1 (MERGED front-end):
//  blocks 0..1371  : cond_maps (o-major, wave per o)
//  block 1372      : loss_dis
//  blocks 1373..1449: sim (fn redundant in-block, swizzled LDS)
__global__ void k_front(const float* __restrict__ fc, const float* __restrict__ cw,
                        const float* __restrict__ cb, float* __restrict__ cm,
                        float* __restrict__ loss_out,
                        const float* __restrict__ fp, float* __restrict__ swl) {
    __shared__ float4 smem4[640];        // 10240 B (aliased: sfc | fnq)
    float* sfc = (float*)smem4;
    int bid = blockIdx.x, t = threadIdx.x;
    int wave = t >> 6, lane = t & 63;

    if (bid < 1373) {
        for (int i = t; i < C_*D_; i += 256) sfc[i] = fc[i];
        __syncthreads();

        if (bid == 1372) {
            for (int c = wave; c < C_; c += 4) {
                float ss = 0.f;
                for (int d = lane; d < D_; d += 64) { float v = sfc[c*D_+d]; ss += v*v; }
                ss = wave_sum(ss);
                float inv = 1.f / fmaxf(sqrtf(ss), 1e-12f);
                for (int d = lane; d < D_; d += 64) sfc[c*D_+d] *= inv;
            }
            __syncthreads();
            if (wave == 0) {
                float acc = 0.f;
                for (int i = 0; i < C_; ++i)
                    for (int j = i+1; j < C_; ++j) {
                        float p = 0.f;
                        for (int d = lane; d < D_; d += 64) p += sfc[i*D_+d]*sfc[j*D_+d];
                        p = wave_sum(p);
                        acc += fmaxf(p, 0.f);
                    }
                if (lane == 0) *loss_out = acc * (1.f/10.f);
            }
            return;
        }

        int o = bid*4 + wave;            // < 5488
        const float4* w4 = (const float4*)(cw + (size_t)o*D_);
        float4 wa = w4[lane], wb = w4[lane+64];
        float bias = cb[o];
        float keep = 0.f;
#pragma unroll
        for (int c = 0; c < C_; ++c) {
            const float4* f4 = (const float4*)(sfc + c*D_);
            float s = dot4(wa, f4[lane]) + dot4(wb, f4[lane+64]);
            s = wave_sum(s);
            if (lane == c) keep = s;
        }
        if (lane < C_) cm[lane*5488 + o] = keep + bias;
        return;
    }

    // ---- sim part ----
    for (int c = wave; c < C_; c += 4) {
        const float4* f8 = (const float4*)(fc + c*D_);
        float4 v0 = f8[lane*2], v1 = f8[lane*2+1];
        float ss = dot4(v0,v0) + dot4(v1,v1);
        ss = wave_sum(ss);
        float inv = 1.f / fmaxf(sqrtf(ss), 1e-12f);
        v0.x*=inv; v0.y*=inv; v0.z*=inv; v0.w*=inv;
        v1.x*=inv; v1.y*=inv; v1.z*=inv; v1.w*=inv;
        int f0 = lane*2, f1 = lane*2+1;
        smem4[(c*16 + (f0 & 15))*8 + (f0 >> 4)] = v0;
        smem4[(c*16 + (f1 & 15))*8 + (f1 >> 4)] = v1;
    }
    __syncthreads();

    int row = t >> 3, seg = t & 7;
    int bl = (bid - 1373)*32 + row;      // < 2464 exactly
    int b = bl / L_, l = bl - b*L_;
    const float4* p4 = ((const float4*)(fp + (size_t)bl*D_)) + seg*16;
    float ss=0.f, s0=0.f, s1=0.f, s2=0.f, s3=0.f, s4=0.f;
#pragma unroll 4
    for (int k = 0; k < 16; ++k) {
        float4 v = p4[k];
        int base = k*8 + seg;
        ss += dot4(v, v);
        s0 += dot4(v, smem4[base]);
        s1 += dot4(v, smem4[128 + base]);
        s2 += dot4(v, smem4[256 + base]);
        s3 += dot4(v, smem4[384 + base]);
        s4 += dot4(v, smem4[512 + base]);
    }
#pragma unroll
    for (int off = 1; off < 8; off <<= 1) {
        ss += __shfl_xor(ss,off,64);
        s0 += __shfl_xor(s0,off,64); s1 += __shfl_xor(s1,off,64);
        s2 += __shfl_xor(s2,off,64); s3 += __shfl_xor(s3,off,64);
        s4 += __shfl_xor(s4,off,64);
    }
    if (seg == 0) {
        float inv = 1.f / fmaxf(sqrtf(ss), 1e-12f);
        float inv2 = inv*inv;
        swl[((size_t)(b*C_+0))*L_ + l] = s0*inv2;
        swl[((size_t)(b*C_+1))*L_ + l] = s1*inv2;
        swl[((size_t)(b*C_+2))*L_ + l] = s2*inv2;
        swl[((size_t)(b*C_+3))*L_ + l] = s3*inv2;
        swl[((size_t)(b*C_+4))*L_ + l] = s4*inv2;
    }
}

// K2: Q[b,c,d] = sum_l swl[b,c,l] * fp[b,l,d]   grid (2, B_), 256 thr
__global__ void k_Q(const float* __restrict__ fp, const float* __restrict__ swl,
                    float* __restrict__ Q) {
    __shared__ float sw[C_][80];
    int b = blockIdx.y;
    int t = threadIdx.x;
    for (int i = t; i < C_*L_; i += 256) { int c = i/L_, l = i - c*L_; sw[c][l] = swl[((size_t)(b*C_+c))*L_ + l]; }
    __syncthreads();
    int d = blockIdx.x*256 + t;
    float a0=0.f, a1=0.f, a2=0.f, a3=0.f, a4=0.f;
    const float* f = fp + (size_t)b*L_*D_ + d;
    for (int l = 0; l < L_; ++l) {
        float v = f[(size_t)l*D_];
        a0 += sw[0][l]*v; a1 += sw[1][l]*v; a2 += sw[2][l]*v;
        a3 += sw[3][l]*v; a4 += sw[4][l]*v;
    }
    Q[(size_t)(b*C_+0)*D_ + d] = a0;
    Q[(size_t)(b*C_+1)*D_ + d] = a1;
    Q[(size_t)(b*C_+2)*D_ + d] = a2;
    Q[(size_t)(b*C_+3)*D_ + d] = a3;
    Q[(size_t)(b*C_+4)*D_ + d] = a4;
}

// K3 (MERGED, INTERLEAVED): bid%4==0 && bid<1500 -> conv (conv_id = bid/4);
// else pw. Conv lane-remap: chq = wave (conflict-free im reads, ~10-addr
// weight loads); cross-chq combine via LDS aliased onto im after barrier.
__global__ void k_conv_pw(const float* __restrict__ cm,
                          const float* __restrict__ w1, const float* __restrict__ bb1,
                          const float* __restrict__ w2, const float* __restrict__ bb2,
                          const float* __restrict__ w3, const float* __restrict__ bb3,
                          const float* __restrict__ w4, const float* __restrict__ bb4,
                          float* __restrict__ o1, float* __restrict__ o2,
                          float* __restrict__ o3, float* __restrict__ o4,
                          const float* __restrict__ w1b, const float* __restrict__ b1b,
                          const float* __restrict__ w2b, const float* __restrict__ b2b,
                          const float* __restrict__ w3b, const float* __restrict__ b3b,
                          const float* __restrict__ w4b, const float* __restrict__ b4b,
                          const float* __restrict__ w5w, const float* __restrict__ b5w,
                          const float* __restrict__ w5b, const float* __restrict__ b5b,
                          float* __restrict__ fcb,
                          const float* __restrict__ tex, const float* __restrict__ Q,
                          float* __restrict__ pw, float2* __restrict__ pstat) {
    __shared__ float4 smem4[3052];       // 48832 B
    __shared__ float sp[112];
    int bid = blockIdx.x;
    int t = threadIdx.x;
    bool is_conv = (bid < 1500) && ((bid & 3) == 0);

    if (!is_conv) {
        // ---- pw part ----
        int p = (bid >= 1500) ? (bid - 375) : (bid - 1 - (bid >> 2));
        float4* qs = smem4;
        float* sraw = (float*)(smem4 + 640);   // [C_][32]
        int bx = p % NPW_, b = p / NPW_;
        {
            const float4* q4 = (const float4*)(Q + (size_t)b*C_*D_);
            for (int i = t; i < C_*128; i += 256) {
                int c = i >> 7, f = i & 127;
                qs[(c*16 + (f & 15))*8 + (f >> 4)] = q4[i];
            }
        }
        __syncthreads();
        int row = t >> 3, seg = t & 7;
        int j = bx*32 + row;
        bool valid = (j < J_);
        int jc = valid ? j : (J_-1);
        const float4* tp = (const float4*)(tex + ((size_t)(b*J_ + jc))*D_ + seg*64);
        float ss=0.f, s0=0.f, s1=0.f, s2=0.f, s3=0.f, s4=0.f;
#pragma unroll 4
        for (int k = 0; k < 16; ++k) {
            float4 v = tp[k];
            int base = k*8 + seg;
            ss += dot4(v, v);
            s0 += dot4(v, qs[base]);
            s1 += dot4(v, qs[128 + base]);
            s2 += dot4(v, qs[256 + base]);
            s3 += dot4(v, qs[384 + base]);
            s4 += dot4(v, qs[512 + base]);
        }
#pragma unroll
        for (int off = 1; off < 8; off <<= 1) {
            ss += __shfl_xor(ss,off,64);
            s0 += __shfl_xor(s0,off,64); s1 += __shfl_xor(s1,off,64);
            s2 += __shfl_xor(s2,off,64); s3 += __shfl_xor(s3,off,64);
            s4 += __shfl_xor(s4,off,64);
        }
        if (seg == 0) {
            float inv = 1.f / fmaxf(sqrtf(ss), 1e-12f);
            float r0 = s0*inv, r1 = s1*inv, r2 = s2*inv, r3 = s3*inv, r4 = s4*inv;
            if (valid) {
                pw[((size_t)(b*C_+0))*J_ + j] = r0;
                pw[((size_t)(b*C_+1))*J_ + j] = r1;
                pw[((size_t)(b*C_+2))*J_ + j] = r2;
                pw[((size_t)(b*C_+3))*J_ + j] = r3;
                pw[((size_t)(b*C_+4))*J_ + j] = r4;
                sraw[0*32+row]=r0; sraw[1*32+row]=r1; sraw[2*32+row]=r2;
                sraw[3*32+row]=r3; sraw[4*32+row]=r4;
            } else {
                sraw[0*32+row]=-1e30f; sraw[1*32+row]=-1e30f; sraw[2*32+row]=-1e30f;
                sraw[3*32+row]=-1e30f; sraw[4*32+row]=-1e30f;
            }
        }
        __syncthreads();
        if (t < C_*32) {
            int c = t >> 5, r2 = t & 31;
            float v = sraw[c*32 + r2];
            float m = v;
#pragma unroll
            for (int off = 1; off < 32; off <<= 1) m = fmaxf(m, __shfl_xor(m,off,32));
            float e = (v > -1e29f) ? expf(v - m) : 0.f;
#pragma unroll
            for (int off = 1; off < 32; off <<= 1) e += __shfl_xor(e,off,32);
            if (r2 == 0) pstat[(size_t)(bx*B_ + b)*C_ + c] = make_float2(m, e);
        }
        return;
    }

    // ---- conv part ----
    int conv_id = bid >> 2;
    float* im = (float*)smem4;           // 12096 floats
    int c  = conv_id / 75;
    int bx = conv_id - c*75;
    for (int i = t; i < 112*108; i += 256) im[i] = 0.f;
    __syncthreads();
    const float* cmc = cm + c*5488;
    for (int i = t; i < 112*49; i += 256) {
        int ch = i / 49, yx = i - ch*49;
        int y = yx / 7, x = yx - y*7;
        im[ch*108 + (y+1)*12 + (x+1)] = cmc[i];
    }
    __syncthreads();

    // hyper biases (bx==0) BEFORE im gets aliased
    if (bx == 0) {
        if (t < 112) {
            const float* p = im + t*108;
            float s = 0.f;
            for (int k = 0; k < 108; ++k) s += p[k];
            sp[t] = s * (1.f/49.f);
        }
        __syncthreads();
        if (t < 225) {
            int rel = t;
            const float* w; const float* bb; int nout; int base;
            if      (rel < 112) {            w=w1b; bb=b1b; nout=112; base=0; }
            else if (rel < 168) { rel-=112;  w=w2b; bb=b2b; nout=56;  base=560; }
            else if (rel < 196) { rel-=168;  w=w3b; bb=b3b; nout=28;  base=840; }
            else if (rel < 210) { rel-=196;  w=w4b; bb=b4b; nout=14;  base=980; }
            else if (rel < 224) { rel-=210;  w=w5w; bb=b5w; nout=14;  base=1050; }
            else                { rel-=224;  w=w5b; bb=b5b; nout=1;   base=1120; }
            float s = bb[rel];
            const float* wr = w + rel*112;
            for (int i = 0; i < 112; ++i) s += sp[i]*wr[i];
            fcb[base + c*nout + rel] = s;
        }
    }

    int oyl = t & 63;
    int chq = t >> 6;
    int oy  = bx*64 + oyl;
    bool ovalid = (oy < 4760);
    int oyc = ovalid ? oy : 0;
    int o_comb = oyc / 7, y = oyc - o_comb*7;
    const float* w; int o;
    if      (o_comb < 512) { w=w1; o=o_comb; }
    else if (o_comb < 640) { w=w2; o=o_comb-512; }
    else if (o_comb < 672) { w=w3; o=o_comb-640; }
    else                   { w=w4; o=o_comb-672; }

    float ac0=0,ac1=0,ac2=0,ac3=0,ac4=0,ac5=0,ac6=0;
    const float* wbase = w + ((size_t)o*112 + chq*28)*9;
    const float* imc   = im + (chq*28)*108 + y*12;
#pragma unroll 2
    for (int ch = 0; ch < 28; ++ch) {
        const float* wk = wbase + ch*9;
        const float* ii = imc + ch*108;
        float w0=wk[0],w1_=wk[1],w2_=wk[2],w3_=wk[3],w4_=wk[4],w5_=wk[5],w6_=wk[6],w7_=wk[7],w8_=wk[8];
#pragma unroll
        for (int ky = 0; ky < 3; ++ky) {
            const float* row = ii + ky*12;
            float4 ra = *(const float4*)(row);
            float4 rb = *(const float4*)(row + 4);
            float  rc = row[8];
            float r0=ra.x,r1=ra.y,r2=ra.z,r3=ra.w,r4=rb.x,r5=rb.y,r6=rb.z,r7=rb.w,r8=rc;
            float wk0 = (ky==0)?w0:((ky==1)?w3_:w6_);
            float wk1 = (ky==0)?w1_:((ky==1)?w4_:w7_);
            float wk2 = (ky==0)?w2_:((ky==1)?w5_:w8_);
            ac0 += r0*wk0 + r1*wk1 + r2*wk2;
            ac1 += r1*wk0 + r2*wk1 + r3*wk2;
            ac2 += r2*wk0 + r3*wk1 + r4*wk2;
            ac3 += r3*wk0 + r4*wk1 + r5*wk2;
            ac4 += r4*wk0 + r5*wk1 + r6*wk2;
            ac5 += r5*wk0 + r6*wk1 + r7*wk2;
            ac6 += r6*wk0 + r7*wk1 + r8*wk2;
        }
    }
    __syncthreads();                     // all im reads done
    float* partb = im;                   // alias: 4*64*9 = 2304 floats
    {
        int pb = (chq*64 + oyl)*9;
        partb[pb+0]=ac0; partb[pb+1]=ac1; partb[pb+2]=ac2; partb[pb+3]=ac3;
        partb[pb+4]=ac4; partb[pb+5]=ac5; partb[pb+6]=ac6;
    }
    __syncthreads();
    for (int i = t; i < 448; i += 256) {
        int oyl2 = i / 7, x = i - oyl2*7;
        int oy2 = bx*64 + oyl2;
        if (oy2 < 4760) {
            float s = partb[(0*64+oyl2)*9+x] + partb[(1*64+oyl2)*9+x]
                    + partb[(2*64+oyl2)*9+x] + partb[(3*64+oyl2)*9+x];
            int oc = oy2/7, yy = oy2 - oc*7;
            const float* bias; float* outp; int oo;
            if      (oc < 512) { bias=bb1; outp=o1 + (size_t)c*512*49; oo=oc; }
            else if (oc < 640) { bias=bb2; outp=o2 + (size_t)c*128*49; oo=oc-512; }
            else if (oc < 672) { bias=bb3; outp=o3 + (size_t)c*32*49;  oo=oc-640; }
            else               { bias=bb4; outp=o4 + (size_t)c*8*49;   oo=oc-672; }
            outp[oo*49 + yy*7 + x] = s + bias[oo];
        }
    }
}

// K4: ftf partials [tex pass #2]; pre-phase combines 37 partial stats -> (m, 1/denom).
__global__ void k_ftf(const float* __restrict__ tex, const float* __restrict__ pwraw,
                      const float2* __restrict__ pstat, float* __restrict__ part) {
    __shared__ float sw[C_][JC_];
    __shared__ float2 sL[C_];
    int chunk = blockIdx.x, b = blockIdx.y;
    int t = threadIdx.x;                 // 512
    int wave = t >> 6, lane = t & 63;
    if (wave < C_) {
        float2 pv = (lane < NPW_) ? pstat[(size_t)(lane*B_ + b)*C_ + wave]
                                  : make_float2(-1e30f, 0.f);
        float m = wave_max(pv.x);
        float contrib = (lane < NPW_) ? pv.y * expf(pv.x - m) : 0.f;
        float denom = wave_sum(contrib);
        if (lane == 0) sL[wave] = make_float2(m, 1.f/denom);
    }
    __syncthreads();
    int j0 = chunk*JC_;
    int jn = min(JC_, J_ - j0);
    if (t < C_*JC_) {
        int c = t >> 6, jj = t & 63;
        float2 ms = sL[c];
        sw[c][jj] = (jj < jn)
            ? expf(pwraw[((size_t)(b*C_+c))*J_ + j0 + jj] - ms.x) * ms.y
            : 0.f;
    }
    __syncthreads();
    float acc0=0.f, acc1=0.f, acc2=0.f, acc3=0.f, acc4=0.f;
    const float* tp = tex + ((size_t)b*J_ + j0)*D_ + t;
    for (int jj = 0; jj < jn; ++jj) {
        float v = tp[(size_t)jj*D_];
        acc0 += v*sw[0][jj]; acc1 += v*sw[1][jj]; acc2 += v*sw[2][jj];
        acc3 += v*sw[3][jj]; acc4 += v*sw[4][jj];
    }
    size_t base = (((size_t)chunk*B_ + b)*C_)*D_ + t;
    part[base               ] = acc0;
    part[base +   (size_t)D_] = acc1;
    part[base + 2*(size_t)D_] = acc2;
    part[base + 3*(size_t)D_] = acc3;
    part[base + 4*(size_t)D_] = acc4;
}

// K5: fused chunk-reduce + eot + fq + TargetNet per (b,c) block.
__global__ void k_fq_target(const float* __restrict__ part, const float* __restrict__ eot,
                            const float* __restrict__ qw, const float* __restrict__ qb,
                            const float* __restrict__ g1w, const float* __restrict__ g2w,
                            const float* __restrict__ g3w, const float* __restrict__ g4w,
                            const float* __restrict__ fcb, float* __restrict__ out) {
    int bc = blockIdx.x; int b = bc / C_; int c = bc - b*C_;
    __shared__ float sf[D_];
    __shared__ float sa[224], sb[112];
    int t = threadIdx.x;                 // 256

    float s0 = 0.f, s1 = 0.f;
    for (int ch = 0; ch < NCH_; ++ch) {
        const float* p = part + ((size_t)ch*(B_*C_) + bc)*D_;
        s0 += p[t]; s1 += p[t+256];
    }
    sf[t]     = s0 * eot[b*D_ + t];
    sf[t+256] = s1 * eot[b*D_ + t + 256];
    __syncthreads();

    if (t < 224) {
        const float4* w4 = (const float4*)(qw + (size_t)t*D_);
        const float4* s4 = (const float4*)sf;
        float acc = 0.f;
#pragma unroll 4
        for (int i = 0; i < 128; ++i) acc += dot4(s4[i], w4[i]);
        sa[t] = acc + qb[t];
    }
    __syncthreads();

    if (t < 112) {
        const float* w = g1w + (size_t)c*25088 + t*224;
        float s = fcb[c*112 + t];
        for (int k = 0; k < 224; ++k) s += w[k]*sa[k];
        sb[t] = 1.f/(1.f+expf(-s));
    }
    __syncthreads();
    if (t < 56) {
        const float* w = g2w + (size_t)c*6272 + t*112;
        float s = fcb[560 + c*56 + t];
        for (int k = 0; k < 112; ++k) s += w[k]*sb[k];
        sa[t] = 1.f/(1.f+expf(-s));
    }
    __syncthreads();
    if (t < 28) {
        const float* w = g3w + (size_t)c*1568 + t*56;
        float s = fcb[840 + c*28 + t];
        for (int k = 0; k < 56; ++k) s += w[k]*sa[k];
        sb[t] = 1.f/(1.f+expf(-s));
    }
    __syncthreads();
    if (t < 14) {
        const float* w = g4w + (size_t)c*392 + t*28;
        float s = fcb[980 + c*14 + t];
        for (int k = 0; k < 28; ++k) s += w[k]*sb[k];
        sa[t] = 1.f/(1.f+expf(-s));
    }
    __syncthreads();
    if (t == 0) {
        float s = fcb[1120 + c];
        for (int p = 0; p < 14; ++p) s += sa[p]*fcb[1050 + c*14 + p];
        out[b*C_ + c] = s;
    }
}

extern "C" void kernel_launch(void* const* d_in, const int* in_sizes, int n_in,
                              void* d_out, int out_size, void* d_ws, size_t ws_size,
                              hipStream_t stream) {
    (void)in_sizes; (void)n_in; (void)out_size; (void)ws_size;
    const float* tex   = (const float*)d_in[0];
    const float* fp    = (const float*)d_in[1];
    const float* eot   = (const float*)d_in[2];
    const float* fcond = (const float*)d_in[3];
    const float* qw    = (const float*)d_in[4];
    const float* qb    = (const float*)d_in[5];
    const float* cw    = (const float*)d_in[6];
    const float* cb    = (const float*)d_in[7];
    const float* w1c   = (const float*)d_in[8];  const float* b1c = (const float*)d_in[9];
    const float* w2c   = (const float*)d_in[10]; const float* b2c = (const float*)d_in[11];
    const float* w3c   = (const float*)d_in[12]; const float* b3c = (const float*)d_in[13];
    const float* w4c   = (const float*)d_in[14]; const float* b4c = (const float*)d_in[15];
    const float* f1bw  = (const float*)d_in[16]; const float* f1bb = (const float*)d_in[17];
    const float* f2bw  = (const float*)d_in[18]; const float* f2bb = (const float*)d_in[19];
    const float* f3bw  = (const float*)d_in[20]; const float* f3bb = (const float*)d_in[21];
    const float* f4bw  = (const float*)d_in[22]; const float* f4bb = (const float*)d_in[23];
    const float* f5ww  = (const float*)d_in[24]; const float* f5wb = (const float*)d_in[25];
    const float* f5bw  = (const float*)d_in[26]; const float* f5bb = (const float*)d_in[27];
    float* out = (float*)d_out;

    float* ws     = (float*)d_ws;
    float* Qb     = ws;                          // 81920
    float* pw     = Qb + 81920;                  // 189120
    float* part   = pw + 189120;                 // 19*81920 = 1556480
    float* pstat  = part + 1556480;              // 37*32*5*2 = 11840 (8B-aligned)
    float* cm     = pstat + 11840;               // 27440
    float* g1w    = cm + 27440;                  // 125440
    float* g2w    = g1w + 125440;                // 31360
    float* g3w    = g2w + 31360;                 // 7840
    float* g4w    = g3w + 7840;                  // 1960
    float* fcb    = g4w + 1960;                  // 1125
    float* swl    = fcb + 1125;                  // 12320

    k_front<<<1450, 256, 0, stream>>>(fcond, cw, cb, cm, out + B_*C_, fp, swl);
    k_Q<<<dim3(2, B_), 256, 0, stream>>>(fp, swl, Qb);
    k_conv_pw<<<1559, 256, 0, stream>>>(cm, w1c, b1c, w2c, b2c, w3c, b3c, w4c, b4c,
                                        g1w, g2w, g3w, g4w,
                                        f1bw, f1bb, f2bw, f2bb, f3bw, f3bb,
                                        f4bw, f4bb, f5ww, f5wb, f5bw, f5bb, fcb,
                                        tex, Qb, pw, (float2*)pstat);
    k_ftf<<<dim3(NCH_, B_), 512, 0, stream>>>(tex, pw, (const float2*)pstat, part);
    k_fq_target<<<B_*C_, 256, 0, stream>>>(part, eot, qw, qb,
                                           g1w, g2w, g3w, g4w, fcb, out);
}

// Round 17
// 90.538 us; speedup vs baseline: 1.1228x; 1.1228x over previous
//
#include <hip/hip_runtime.h>
#include <hip/hip_bf16.h>
#include <math.h>

#define B_   32
#define J_   1182      // V*P = 6*197
#define D_   512
#define L_   77
#define C_   5
#define JC_  64        // j-chunk for ftf
#define NCH_ 19        // ceil(1182/64)
#define NPW_ 74        // pw chunks of 16 rows
#define JPW_ 16

__device__ __forceinline__ float dot4(float4 a, float4 b) {
    return a.x*b.x + a.y*b.y + a.z*b.z + a.w*b.w;
}

__device__ __forceinline__ float wave_sum(float v) {
#pragma unroll
    for (int off = 32; off > 0; off >>= 1) v += __shfl_xor(v, off, 64);
    return v;
}

__device__ __forceinline__ float wave_max(float v) {
#pragma unroll
    for (int off = 32; off > 0; off >>= 1) v = fmaxf(v, __shfl_xor(v, off, 64));
    return v;
}

// K1 (MERGED front-end): 0..1371 cond_maps | 1372 loss | 1373..1449 sim
__global__ void k_front(const float* __restrict__ fc, const float* __restrict__ cw,
                        const float* __restrict__ cb, float* __restrict__ cm,
                        float* __restrict__ loss_out,
                        const float* __restrict__ fp, float* __restrict__ swl) {
    __shared__ float4 smem4[640];        // 10240 B
    float* sfc = (float*)smem4;
    int bid = blockIdx.x, t = threadIdx.x;
    int wave = t >> 6, lane = t & 63;

    if (bid < 1373) {
        for (int i = t; i < C_*D_; i += 256) sfc[i] = fc[i];
        __syncthreads();

        if (bid == 1372) {
            for (int c = wave; c < C_; c += 4) {
                float ss = 0.f;
                for (int d = lane; d < D_; d += 64) { float v = sfc[c*D_+d]; ss += v*v; }
                ss = wave_sum(ss);
                float inv = 1.f / fmaxf(sqrtf(ss), 1e-12f);
                for (int d = lane; d < D_; d += 64) sfc[c*D_+d] *= inv;
            }
            __syncthreads();
            if (wave == 0) {
                float acc = 0.f;
                for (int i = 0; i < C_; ++i)
                    for (int j = i+1; j < C_; ++j) {
                        float p = 0.f;
                        for (int d = lane; d < D_; d += 64) p += sfc[i*D_+d]*sfc[j*D_+d];
                        p = wave_sum(p);
                        acc += fmaxf(p, 0.f);
                    }
                if (lane == 0) *loss_out = acc * (1.f/10.f);
            }
            return;
        }

        int o = bid*4 + wave;            // < 5488
        const float4* w4 = (const float4*)(cw + (size_t)o*D_);
        float4 wa = w4[lane], wb = w4[lane+64];
        float bias = cb[o];
        float keep = 0.f;
#pragma unroll
        for (int c = 0; c < C_; ++c) {
            const float4* f4 = (const float4*)(sfc + c*D_);
            float s = dot4(wa, f4[lane]) + dot4(wb, f4[lane+64]);
            s = wave_sum(s);
            if (lane == c) keep = s;
        }
        if (lane < C_) cm[lane*5488 + o] = keep + bias;
        return;
    }

    // ---- sim part ----
    for (int c = wave; c < C_; c += 4) {
        const float4* f8 = (const float4*)(fc + c*D_);
        float4 v0 = f8[lane*2], v1 = f8[lane*2+1];
        float ss = dot4(v0,v0) + dot4(v1,v1);
        ss = wave_sum(ss);
        float inv = 1.f / fmaxf(sqrtf(ss), 1e-12f);
        v0.x*=inv; v0.y*=inv; v0.z*=inv; v0.w*=inv;
        v1.x*=inv; v1.y*=inv; v1.z*=inv; v1.w*=inv;
        int f0 = lane*2, f1 = lane*2+1;
        smem4[(c*16 + (f0 & 15))*8 + (f0 >> 4)] = v0;
        smem4[(c*16 + (f1 & 15))*8 + (f1 >> 4)] = v1;
    }
    __syncthreads();

    int row = t >> 3, seg = t & 7;
    int bl = (bid - 1373)*32 + row;      // < 2464 exactly
    int b = bl / L_, l = bl - b*L_;
    const float4* p4 = ((const float4*)(fp + (size_t)bl*D_)) + seg*16;
    float ss=0.f, s0=0.f, s1=0.f, s2=0.f, s3=0.f, s4=0.f;
#pragma unroll 4
    for (int k = 0; k < 16; ++k) {
        float4 v = p4[k];
        int base = k*8 + seg;
        ss += dot4(v, v);
        s0 += dot4(v, smem4[base]);
        s1 += dot4(v, smem4[128 + base]);
        s2 += dot4(v, smem4[256 + base]);
        s3 += dot4(v, smem4[384 + base]);
        s4 += dot4(v, smem4[512 + base]);
    }
#pragma unroll
    for (int off = 1; off < 8; off <<= 1) {
        ss += __shfl_xor(ss,off,64);
        s0 += __shfl_xor(s0,off,64); s1 += __shfl_xor(s1,off,64);
        s2 += __shfl_xor(s2,off,64); s3 += __shfl_xor(s3,off,64);
        s4 += __shfl_xor(s4,off,64);
    }
    if (seg == 0) {
        float inv = 1.f / fmaxf(sqrtf(ss), 1e-12f);
        float inv2 = inv*inv;
        swl[((size_t)(b*C_+0))*L_ + l] = s0*inv2;
        swl[((size_t)(b*C_+1))*L_ + l] = s1*inv2;
        swl[((size_t)(b*C_+2))*L_ + l] = s2*inv2;
        swl[((size_t)(b*C_+3))*L_ + l] = s3*inv2;
        swl[((size_t)(b*C_+4))*L_ + l] = s4*inv2;
    }
}

// K2: Q[b,c,d] = sum_l swl[b,c,l] * fp[b,l,d]   grid (2, B_), 256 thr
__global__ void k_Q(const float* __restrict__ fp, const float* __restrict__ swl,
                    float* __restrict__ Q) {
    __shared__ float sw[C_][80];
    int b = blockIdx.y;
    int t = threadIdx.x;
    for (int i = t; i < C_*L_; i += 256) { int c = i/L_, l = i - c*L_; sw[c][l] = swl[((size_t)(b*C_+c))*L_ + l]; }
    __syncthreads();
    int d = blockIdx.x*256 + t;
    float a0=0.f, a1=0.f, a2=0.f, a3=0.f, a4=0.f;
    const float* f = fp + (size_t)b*L_*D_ + d;
    for (int l = 0; l < L_; ++l) {
        float v = f[(size_t)l*D_];
        a0 += sw[0][l]*v; a1 += sw[1][l]*v; a2 += sw[2][l]*v;
        a3 += sw[3][l]*v; a4 += sw[4][l]*v;
    }
    Q[(size_t)(b*C_+0)*D_ + d] = a0;
    Q[(size_t)(b*C_+1)*D_ + d] = a1;
    Q[(size_t)(b*C_+2)*D_ + d] = a2;
    Q[(size_t)(b*C_+3)*D_ + d] = a3;
    Q[(size_t)(b*C_+4)*D_ + d] = a4;
}

// K3 (MERGED): bid<375 conv (conflict-free remap); bid>=375 pw with COALESCED
// LDS staging (round-9 phases 0/1/2): 16-row chunks, stride-576 swizzle.
__global__ void k_conv_pw(const float* __restrict__ cm,
                          const float* __restrict__ w1, const float* __restrict__ bb1,
                          const float* __restrict__ w2, const float* __restrict__ bb2,
                          const float* __restrict__ w3, const float* __restrict__ bb3,
                          const float* __restrict__ w4, const float* __restrict__ bb4,
                          float* __restrict__ o1, float* __restrict__ o2,
                          float* __restrict__ o3, float* __restrict__ o4,
                          const float* __restrict__ w1b, const float* __restrict__ b1b,
                          const float* __restrict__ w2b, const float* __restrict__ b2b,
                          const float* __restrict__ w3b, const float* __restrict__ b3b,
                          const float* __restrict__ w4b, const float* __restrict__ b4b,
                          const float* __restrict__ w5w, const float* __restrict__ b5w,
                          const float* __restrict__ w5b, const float* __restrict__ b5b,
                          float* __restrict__ fcb,
                          const float* __restrict__ tex, const float* __restrict__ Q,
                          float* __restrict__ pw, float2* __restrict__ pstat) {
    __shared__ float smem[12352];        // 49408 B, aliased per path
    int bid = blockIdx.x;
    int t = threadIdx.x;

    if (bid >= 375) {
        // ---- pw part: stage 16 tex rows + Q coalesced -> LDS, score from LDS ----
        float* stex = smem;              // 16*576 = 9216
        float* sq   = smem + 9216;       // 5*576  = 2880
        float* srawT = smem + 12096;     // [16][8] = 128
        int p = bid - 375;
        int bx = p % NPW_, b = p / NPW_;
        int j0 = bx*JPW_;
        int jn = min(JPW_, J_ - j0);

        {
            const float4* q4 = (const float4*)(Q + (size_t)b*C_*D_);
            for (int i = t; i < C_*128; i += 256) {
                int c = i >> 7, col4 = i & 127;
                *(float4*)(sq + c*576 + col4*4 + ((col4>>3)<<2)) = q4[i];
            }
            const float4* t4 = (const float4*)(tex + ((size_t)(b*J_ + j0))*D_);
#pragma unroll
            for (int n = 0; n < 8; ++n) {
                int i = n*256 + t;       // < 2048
                int row = i >> 7, col4 = i & 127;
                if (row < jn)
                    *(float4*)(stex + row*576 + col4*4 + ((col4>>3)<<2)) = t4[i];
            }
        }
        __syncthreads();

        {
            int row = t >> 4, seg = t & 15;
            const float* sr = stex + row*576;
            float ss=0.f, s0=0.f, s1=0.f, s2=0.f, s3=0.f, s4=0.f;
#pragma unroll
            for (int k = 0; k < 8; ++k) {
                int col4 = seg*8 + k;
                int wa = col4*4 + ((col4>>3)<<2);
                float4 v = *(const float4*)(sr + wa);
                ss += dot4(v, v);
                s0 += dot4(v, *(const float4*)(sq +          wa));
                s1 += dot4(v, *(const float4*)(sq +   576 + wa));
                s2 += dot4(v, *(const float4*)(sq + 2*576 + wa));
                s3 += dot4(v, *(const float4*)(sq + 3*576 + wa));
                s4 += dot4(v, *(const float4*)(sq + 4*576 + wa));
            }
#pragma unroll
            for (int off = 1; off < 16; off <<= 1) {
                ss += __shfl_xor(ss,off,64);
                s0 += __shfl_xor(s0,off,64); s1 += __shfl_xor(s1,off,64);
                s2 += __shfl_xor(s2,off,64); s3 += __shfl_xor(s3,off,64);
                s4 += __shfl_xor(s4,off,64);
            }
            if (seg == 0) {
                if (row < jn) {
                    float inv = 1.f / fmaxf(sqrtf(ss), 1e-12f);
                    float r0=s0*inv, r1=s1*inv, r2=s2*inv, r3=s3*inv, r4=s4*inv;
                    int j = j0 + row;
                    pw[((size_t)(b*C_+0))*J_ + j] = r0;
                    pw[((size_t)(b*C_+1))*J_ + j] = r1;
                    pw[((size_t)(b*C_+2))*J_ + j] = r2;
                    pw[((size_t)(b*C_+3))*J_ + j] = r3;
                    pw[((size_t)(b*C_+4))*J_ + j] = r4;
                    srawT[row*8+0]=r0; srawT[row*8+1]=r1; srawT[row*8+2]=r2;
                    srawT[row*8+3]=r3; srawT[row*8+4]=r4;
                } else {
                    srawT[row*8+0]=-1e30f; srawT[row*8+1]=-1e30f; srawT[row*8+2]=-1e30f;
                    srawT[row*8+3]=-1e30f; srawT[row*8+4]=-1e30f;
                }
            }
        }
        __syncthreads();

        {
            int wave = t >> 6, lane = t & 63;
            bool act = (wave == 0) || (wave == 1 && lane < 16);
            if (act) {
                int c = (wave == 0) ? (lane >> 4) : 4;
                int row = lane & 15;
                float v = srawT[row*8+c];
                float m = v;
#pragma unroll
                for (int off = 1; off < 16; off <<= 1) m = fmaxf(m, __shfl_xor(m,off,64));
                float e = (row < jn) ? expf(v - m) : 0.f;
                float s = e;
#pragma unroll
                for (int off = 1; off < 16; off <<= 1) s += __shfl_xor(s,off,64);
                if (row == 0) pstat[(size_t)(bx*B_+b)*C_ + c] = make_float2(m, s);
            }
        }
        return;
    }

    // ---- conv part (conflict-free remap: chq = wave, lane = oy) ----
    float* im = smem;                    // 12096 floats
    float* sp = smem + 12096;            // 112 floats
    int c  = bid / 75;
    int bx = bid - c*75;
    for (int i = t; i < 112*108; i += 256) im[i] = 0.f;
    __syncthreads();
    const float* cmc = cm + c*5488;
    for (int i = t; i < 112*49; i += 256) {
        int ch = i / 49, yx = i - ch*49;
        int y = yx / 7, x = yx - y*7;
        im[ch*108 + (y+1)*12 + (x+1)] = cmc[i];
    }
    __syncthreads();

    if (bx == 0) {
        if (t < 112) {
            const float* p = im + t*108;
            float s = 0.f;
            for (int k = 0; k < 108; ++k) s += p[k];
            sp[t] = s * (1.f/49.f);
        }
        __syncthreads();
        if (t < 225) {
            int rel = t;
            const float* w; const float* bb; int nout; int base;
            if      (rel < 112) {            w=w1b; bb=b1b; nout=112; base=0; }
            else if (rel < 168) { rel-=112;  w=w2b; bb=b2b; nout=56;  base=560; }
            else if (rel < 196) { rel-=168;  w=w3b; bb=b3b; nout=28;  base=840; }
            else if (rel < 210) { rel-=196;  w=w4b; bb=b4b; nout=14;  base=980; }
            else if (rel < 224) { rel-=210;  w=w5w; bb=b5w; nout=14;  base=1050; }
            else                { rel-=224;  w=w5b; bb=b5b; nout=1;   base=1120; }
            float s = bb[rel];
            const float* wr = w + rel*112;
            for (int i = 0; i < 112; ++i) s += sp[i]*wr[i];
            fcb[base + c*nout + rel] = s;
        }
    }

    int oyl = t & 63;
    int chq = t >> 6;
    int oy  = bx*64 + oyl;
    int oyc = (oy < 4760) ? oy : 0;
    int o_comb = oyc / 7, y = oyc - o_comb*7;
    const float* w; int o;
    if      (o_comb < 512) { w=w1; o=o_comb; }
    else if (o_comb < 640) { w=w2; o=o_comb-512; }
    else if (o_comb < 672) { w=w3; o=o_comb-640; }
    else                   { w=w4; o=o_comb-672; }

    float ac0=0,ac1=0,ac2=0,ac3=0,ac4=0,ac5=0,ac6=0;
    const float* wbase = w + ((size_t)o*112 + chq*28)*9;
    const float* imc   = im + (chq*28)*108 + y*12;
#pragma unroll 2
    for (int ch = 0; ch < 28; ++ch) {
        const float* wk = wbase + ch*9;
        const float* ii = imc + ch*108;
        float w0=wk[0],w1_=wk[1],w2_=wk[2],w3_=wk[3],w4_=wk[4],w5_=wk[5],w6_=wk[6],w7_=wk[7],w8_=wk[8];
#pragma unroll
        for (int ky = 0; ky < 3; ++ky) {
            const float* row = ii + ky*12;
            float4 ra = *(const float4*)(row);
            float4 rb = *(const float4*)(row + 4);
            float  rc = row[8];
            float r0=ra.x,r1=ra.y,r2=ra.z,r3=ra.w,r4=rb.x,r5=rb.y,r6=rb.z,r7=rb.w,r8=rc;
            float wk0 = (ky==0)?w0:((ky==1)?w3_:w6_);
            float wk1 = (ky==0)?w1_:((ky==1)?w4_:w7_);
            float wk2 = (ky==0)?w2_:((ky==1)?w5_:w8_);
            ac0 += r0*wk0 + r1*wk1 + r2*wk2;
            ac1 += r1*wk0 + r2*wk1 + r3*wk2;
            ac2 += r2*wk0 + r3*wk1 + r4*wk2;
            ac3 += r3*wk0 + r4*wk1 + r5*wk2;
            ac4 += r4*wk0 + r5*wk1 + r6*wk2;
            ac5 += r5*wk0 + r6*wk1 + r7*wk2;
            ac6 += r6*wk0 + r7*wk1 + r8*wk2;
        }
    }
    __syncthreads();                     // all im/sp reads done
    float* partb = im;                   // alias: 4*64*9 = 2304 floats
    {
        int pb = (chq*64 + oyl)*9;
        partb[pb+0]=ac0; partb[pb+1]=ac1; partb[pb+2]=ac2; partb[pb+3]=ac3;
        partb[pb+4]=ac4; partb[pb+5]=ac5; partb[pb+6]=ac6;
    }
    __syncthreads();
    for (int i = t; i < 448; i += 256) {
        int oyl2 = i / 7, x = i - oyl2*7;
        int oy2 = bx*64 + oyl2;
        if (oy2 < 4760) {
            float s = partb[(0*64+oyl2)*9+x] + partb[(1*64+oyl2)*9+x]
                    + partb[(2*64+oyl2)*9+x] + partb[(3*64+oyl2)*9+x];
            int oc = oy2/7, yy = oy2 - oc*7;
            const float* bias; float* outp; int oo;
            if      (oc < 512) { bias=bb1; outp=o1 + (size_t)c*512*49; oo=oc; }
            else if (oc < 640) { bias=bb2; outp=o2 + (size_t)c*128*49; oo=oc-512; }
            else if (oc < 672) { bias=bb3; outp=o3 + (size_t)c*32*49;  oo=oc-640; }
            else               { bias=bb4; outp=o4 + (size_t)c*8*49;   oo=oc-672; }
            outp[oo*49 + yy*7 + x] = s + bias[oo];
        }
    }
}

// K4: ftf partials [tex pass #2]; pre-phase combines 74 partial stats (2/lane).
__global__ void k_ftf(const float* __restrict__ tex, const float* __restrict__ pwraw,
                      const float2* __restrict__ pstat, float* __restrict__ part) {
    __shared__ float sw[C_][JC_];
    __shared__ float2 sL[C_];
    int chunk = blockIdx.x, b = blockIdx.y;
    int t = threadIdx.x;                 // 512
    int wave = t >> 6, lane = t & 63;
    if (wave < C_) {
        float2 pa = (lane < NPW_) ? pstat[(size_t)(lane*B_ + b)*C_ + wave]
                                  : make_float2(-1e30f, 0.f);
        float2 pb = (lane+64 < NPW_) ? pstat[(size_t)((lane+64)*B_ + b)*C_ + wave]
                                     : make_float2(-1e30f, 0.f);
        float m = wave_max(fmaxf(pa.x, pb.x));
        float contrib = pa.y * expf(pa.x - m) + pb.y * expf(pb.x - m);
        float denom = wave_sum(contrib);
        if (lane == 0) sL[wave] = make_float2(m, 1.f/denom);
    }
    __syncthreads();
    int j0 = chunk*JC_;
    int jn = min(JC_, J_ - j0);
    if (t < C_*JC_) {
        int c = t >> 6, jj = t & 63;
        float2 ms = sL[c];
        sw[c][jj] = (jj < jn)
            ? expf(pwraw[((size_t)(b*C_+c))*J_ + j0 + jj] - ms.x) * ms.y
            : 0.f;
    }
    __syncthreads();
    float acc0=0.f, acc1=0.f, acc2=0.f, acc3=0.f, acc4=0.f;
    const float* tp = tex + ((size_t)b*J_ + j0)*D_ + t;
    for (int jj = 0; jj < jn; ++jj) {
        float v = tp[(size_t)jj*D_];
        acc0 += v*sw[0][jj]; acc1 += v*sw[1][jj]; acc2 += v*sw[2][jj];
        acc3 += v*sw[3][jj]; acc4 += v*sw[4][jj];
    }
    size_t base = (((size_t)chunk*B_ + b)*C_)*D_ + t;
    part[base               ] = acc0;
    part[base +   (size_t)D_] = acc1;
    part[base + 2*(size_t)D_] = acc2;
    part[base + 3*(size_t)D_] = acc3;
    part[base + 4*(size_t)D_] = acc4;
}

// K5: fused chunk-reduce + eot + fq + TargetNet per (b,c) block.
__global__ void k_fq_target(const float* __restrict__ part, const float* __restrict__ eot,
                            const float* __restrict__ qw, const float* __restrict__ qb,
                            const float* __restrict__ g1w, const float* __restrict__ g2w,
                            const float* __restrict__ g3w, const float* __restrict__ g4w,
                            const float* __restrict__ fcb, float* __restrict__ out) {
    int bc = blockIdx.x; int b = bc / C_; int c = bc - b*C_;
    __shared__ float sf[D_];
    __shared__ float sa[224], sb[112];
    int t = threadIdx.x;                 // 256

    float s0 = 0.f, s1 = 0.f;
    for (int ch = 0; ch < NCH_; ++ch) {
        const float* p = part + ((size_t)ch*(B_*C_) + bc)*D_;
        s0 += p[t]; s1 += p[t+256];
    }
    sf[t]     = s0 * eot[b*D_ + t];
    sf[t+256] = s1 * eot[b*D_ + t + 256];
    __syncthreads();

    if (t < 224) {
        const float4* w4 = (const float4*)(qw + (size_t)t*D_);
        const float4* s4 = (const float4*)sf;
        float acc = 0.f;
#pragma unroll 4
        for (int i = 0; i < 128; ++i) acc += dot4(s4[i], w4[i]);
        sa[t] = acc + qb[t];
    }
    __syncthreads();

    if (t < 112) {
        const float* w = g1w + (size_t)c*25088 + t*224;
        float s = fcb[c*112 + t];
        for (int k = 0; k < 224; ++k) s += w[k]*sa[k];
        sb[t] = 1.f/(1.f+expf(-s));
    }
    __syncthreads();
    if (t < 56) {
        const float* w = g2w + (size_t)c*6272 + t*112;
        float s = fcb[560 + c*56 + t];
        for (int k = 0; k < 112; ++k) s += w[k]*sb[k];
        sa[t] = 1.f/(1.f+expf(-s));
    }
    __syncthreads();
    if (t < 28) {
        const float* w = g3w + (size_t)c*1568 + t*56;
        float s = fcb[840 + c*28 + t];
        for (int k = 0; k < 56; ++k) s += w[k]*sa[k];
        sb[t] = 1.f/(1.f+expf(-s));
    }
    __syncthreads();
    if (t < 14) {
        const float* w = g4w + (size_t)c*392 + t*28;
        float s = fcb[980 + c*14 + t];
        for (int k = 0; k < 28; ++k) s += w[k]*sb[k];
        sa[t] = 1.f/(1.f+expf(-s));
    }
    __syncthreads();
    if (t == 0) {
        float s = fcb[1120 + c];
        for (int p = 0; p < 14; ++p) s += sa[p]*fcb[1050 + c*14 + p];
        out[b*C_ + c] = s;
    }
}

extern "C" void kernel_launch(void* const* d_in, const int* in_sizes, int n_in,
                              void* d_out, int out_size, void* d_ws, size_t ws_size,
                              hipStream_t stream) {
    (void)in_sizes; (void)n_in; (void)out_size; (void)ws_size;
    const float* tex   = (const float*)d_in[0];
    const float* fp    = (const float*)d_in[1];
    const float* eot   = (const float*)d_in[2];
    const float* fcond = (const float*)d_in[3];
    const float* qw    = (const float*)d_in[4];
    const float* qb    = (const float*)d_in[5];
    const float* cw    = (const float*)d_in[6];
    const float* cb    = (const float*)d_in[7];
    const float* w1c   = (const float*)d_in[8];  const float* b1c = (const float*)d_in[9];
    const float* w2c   = (const float*)d_in[10]; const float* b2c = (const float*)d_in[11];
    const float* w3c   = (const float*)d_in[12]; const float* b3c = (const float*)d_in[13];
    const float* w4c   = (const float*)d_in[14]; const float* b4c = (const float*)d_in[15];
    const float* f1bw  = (const float*)d_in[16]; const float* f1bb = (const float*)d_in[17];
    const float* f2bw  = (const float*)d_in[18]; const float* f2bb = (const float*)d_in[19];
    const float* f3bw  = (const float*)d_in[20]; const float* f3bb = (const float*)d_in[21];
    const float* f4bw  = (const float*)d_in[22]; const float* f4bb = (const float*)d_in[23];
    const float* f5ww  = (const float*)d_in[24]; const float* f5wb = (const float*)d_in[25];
    const float* f5bw  = (const float*)d_in[26]; const float* f5bb = (const float*)d_in[27];
    float* out = (float*)d_out;

    float* ws     = (float*)d_ws;
    float* Qb     = ws;                          // 81920
    float* pw     = Qb + 81920;                  // 189120
    float* part   = pw + 189120;                 // 19*81920 = 1556480
    float* pstat  = part + 1556480;              // 74*32*5*2 = 23680 (8B-aligned)
    float* cm     = pstat + 23680;               // 27440
    float* g1w    = cm + 27440;                  // 125440
    float* g2w    = g1w + 125440;                // 31360
    float* g3w    = g2w + 31360;                 // 7840
    float* g4w    = g3w + 7840;                  // 1960
    float* fcb    = g4w + 1960;                  // 1125
    float* swl    = fcb + 1125;                  // 12320

    k_front<<<1450, 256, 0, stream>>>(fcond, cw, cb, cm, out + B_*C_, fp, swl);
    k_Q<<<dim3(2, B_), 256, 0, stream>>>(fp, swl, Qb);
    k_conv_pw<<<375 + NPW_*B_, 256, 0, stream>>>(cm, w1c, b1c, w2c, b2c, w3c, b3c, w4c, b4c,
                                        g1w, g2w, g3w, g4w,
                                        f1bw, f1bb, f2bw, f2bb, f3bw, f3bb,
                                        f4bw, f4bb, f5ww, f5wb, f5bw, f5bb, fcb,
                                        tex, Qb, pw, (float2*)pstat);
    k_ftf<<<dim3(NCH_, B_), 512, 0, stream>>>(tex, pw, (const float2*)pstat, part);
    k_fq_target<<<B_*C_, 256, 0, stream>>>(part, eot, qw, qb,
                                           g1w, g2w, g3w, g4w, fcb, out);
}